// Round 6
// baseline (214.157 us; speedup 1.0000x reference)
//
#include <hip/hip_runtime.h>
#include <math.h>

#define B 4
#define C 56
#define H 320
#define W 320
#define HC 313
#define WC 313
#define NIMG (H*W)          // 102400
#define NSP  (HC*WC)        // 97969
#define NPIX (B*NSP)        // 391876
#define NPIXP 391936        // 3062*128 (padded pixel count for gram chunks)
#define NM   (B*NIMG)       // 409600
#define BN_EPS 1e-5f
#define GGRID 128

// pool32 tile: 32x32 interior, 39x39 halo
#define PHR 39
#define PNH (PHR*PHR)       // 1521

typedef __attribute__((ext_vector_type(8))) short short8;
typedef __attribute__((ext_vector_type(16))) float float16;

__device__ __forceinline__ unsigned short f2bf(float v) {
  unsigned int u = __float_as_uint(v);
  return (unsigned short)((u + 0x7fffu + ((u >> 16) & 1u)) >> 16);
}

// zero the gram-chunk padding of p_ch (pixels NPIX..NPIXP of each channel plane)
__global__ void padzero_kernel(unsigned short* __restrict__ p_ch) {
  int idx = blockIdx.x*256 + threadIdx.x;
  if (idx < C*(NPIXP-NPIX)) {
    int c = idx / (NPIXP-NPIX), o = idx - c*(NPIXP-NPIX);
    p_ch[(size_t)c*NPIXP + NPIX + o] = 0;
  }
}

// ---------------------------------------------------------------------------
// pool32: one (32x32 tile, b, 8-channel group) per block.
//   per channel: halo->LDS (prefetched), separable 8x8 boxsum, bf16 -> Pt LDS
//   then: Pt -> p_ch (channel-major), channel-partials -> Epart
// ---------------------------------------------------------------------------
__global__ __launch_bounds__(256) void pool32_kernel(
    const float* __restrict__ x, float* __restrict__ Epart,
    unsigned short* __restrict__ p_ch) {
  __shared__ float tin[PHR][40];
  __shared__ float hs[PHR][32];
  __shared__ unsigned short Pt[8][1024];
  const int tid = threadIdx.x;
  int bid = blockIdx.x;
  const int g = bid % 7; bid /= 7;
  const int b = bid & 3; bid >>= 2;
  const int ty = bid / 10, tx = bid - (bid / 10) * 10;
  const int i0 = ty * 32, j0 = tx * 32;
  const float* xg = x + ((size_t)b * C + g * 8) * NIMG;

  float esum[6];
  #pragma unroll
  for (int k = 0; k < 6; ++k) esum[k] = 0.f;

  float cur[6], nxt[6];
  {
    const float* xp = xg;
    #pragma unroll
    for (int k = 0; k < 6; ++k) {
      int idx = tid + k * 256;
      int r = idx / PHR, cc = idx - r * PHR;
      int gi = i0 + r, gj = j0 + cc;
      cur[k] = (idx < PNH && gi < H && gj < W) ? xp[gi * W + gj] : 0.f;
    }
  }

  #pragma unroll
  for (int c = 0; c < 8; ++c) {
    #pragma unroll
    for (int k = 0; k < 6; ++k) {
      int idx = tid + k * 256;
      if (idx < PNH) {
        int r = idx / PHR, cc = idx - r * PHR;
        tin[r][cc] = cur[k];
        if (r < 32 && cc < 32) esum[k] += cur[k];
      }
    }
    __syncthreads();
    if (c < 7) {
      const float* xp = xg + (size_t)(c + 1) * NIMG;
      #pragma unroll
      for (int k = 0; k < 6; ++k) {
        int idx = tid + k * 256;
        int r = idx / PHR, cc = idx - r * PHR;
        int gi = i0 + r, gj = j0 + cc;
        nxt[k] = (idx < PNH && gi < H && gj < W) ? xp[gi * W + gj] : 0.f;
      }
    }
    #pragma unroll
    for (int it = 0; it < 5; ++it) {
      int idx = tid + it * 256;
      if (idx < PHR * 32) {
        int r = idx >> 5, j = idx & 31;
        float s = 0.f;
        #pragma unroll
        for (int d = 0; d < 8; ++d) s += tin[r][j + d];
        hs[r][j] = s;
      }
    }
    __syncthreads();
    #pragma unroll
    for (int it = 0; it < 4; ++it) {
      int idx = tid + it * 256;
      int i = idx >> 5, j = idx & 31;
      float s = 0.f;
      #pragma unroll
      for (int d = 0; d < 8; ++d) s += hs[i + d][j];
      Pt[c][idx] = f2bf(s * (1.f / 64.f));
    }
    #pragma unroll
    for (int k = 0; k < 6; ++k) cur[k] = nxt[k];
  }
  __syncthreads();   // Pt complete

  // Epart: plain stores (each interior pixel owned by exactly one block)
  float* Eb = Epart + ((size_t)g * B + b) * NIMG;
  #pragma unroll
  for (int k = 0; k < 6; ++k) {
    int idx = tid + k * 256;
    if (idx < PNH) {
      int r = idx / PHR, cc = idx - r * PHR;
      if (r < 32 && cc < 32) Eb[(i0 + r) * W + (j0 + cc)] = esum[k];
    }
  }

  // p_ch store: channel-major planes, 2B/lane coalesced within rows
  #pragma unroll
  for (int it = 0; it < 32; ++it) {
    int idx = tid + it * 256;
    int c = idx >> 10, pl = idx & 1023;
    int i = pl >> 5, j = pl & 31;
    int gi = i0 + i, gj = j0 + j;
    if (gi < HC && gj < WC)
      p_ch[(size_t)(g*8 + c) * NPIXP + (size_t)b * NSP + gi * WC + gj] = Pt[c][pl];
  }
}

// ---------------------------------------------------------------------------
// se_pool: E = exp(sum_g Epart / 56) (write), S = 8x8 VALID boxsum of E
// ---------------------------------------------------------------------------
__global__ __launch_bounds__(256) void se_pool_kernel(
    const float* __restrict__ Epart, float* __restrict__ E, float* __restrict__ S) {
  __shared__ float tin[39][40];
  __shared__ float hs[39][33];
  const int b = blockIdx.z;
  const int i0 = blockIdx.y * 32, j0 = blockIdx.x * 32;
  const int tid = threadIdx.x;
  for (int idx = tid; idx < 39 * 39; idx += 256) {
    int r = idx / 39, cc = idx - r * 39;
    int gi = i0 + r, gj = j0 + cc;
    float v = 0.f;
    if (gi < H && gj < W) {
      float s = 0.f;
      #pragma unroll
      for (int g = 0; g < 7; ++g)
        s += Epart[((size_t)g * B + b) * NIMG + gi * W + gj];
      v = expf(s * (1.f / C));
      if (r < 32 && cc < 32) E[(size_t)b * NIMG + gi * W + gj] = v;
    }
    tin[r][cc] = v;
  }
  __syncthreads();
  for (int idx = tid; idx < 39 * 32; idx += 256) {
    int r = idx >> 5, j = idx & 31;
    float s = 0.f;
    #pragma unroll
    for (int d = 0; d < 8; ++d) s += tin[r][j + d];
    hs[r][j] = s;
  }
  __syncthreads();
  for (int idx = tid; idx < 32 * 32; idx += 256) {
    int i = idx >> 5, j = idx & 31;
    int gi = i0 + i, gj = j0 + j;
    if (gi < HC && gj < WC) {
      float s = 0.f;
      #pragma unroll
      for (int d = 0; d < 8; ++d) s += hs[i + d][j];
      S[(size_t)b * NSP + gi * WC + gj] = s;
    }
  }
}

// ---------------------------------------------------------------------------
// gram: G = sum_pix p p^T and gs = sum_pix p, all via MFMA (acc stays in AGPR).
// 5 MFMAs per k-step: quadrants (0,0),(0,1),(1,1) + 2 ones-MFMAs for row sums.
// ---------------------------------------------------------------------------
__global__ __launch_bounds__(256) void gram_kernel(
    const unsigned short* __restrict__ p_ch, float* __restrict__ G,
    float* __restrict__ gs) {
  __shared__ float gacc[64*64];
  __shared__ float sacc[64];
  const int tid = threadIdx.x, wave = tid >> 6, lane = tid & 63;
  for (int i = tid; i < 64*64; i += 256) gacc[i] = 0.f;
  if (tid < 64) sacc[tid] = 0.f;
  __syncthreads();
  const int cl = lane & 31, h = lane >> 5;
  const bool hi_ok = cl < (C - 32);   // channels 32..55 valid
  float16 q00 = {}, q01 = {}, q11 = {}, s0 = {}, s1 = {};
  short8 ones;
  #pragma unroll
  for (int j = 0; j < 8; ++j) ones[j] = (short)0x3F80;   // bf16 1.0
  const unsigned short* baseA0 = p_ch + (size_t)cl * NPIXP;
  const unsigned short* baseA1 = p_ch + (size_t)(32 + cl) * NPIXP;
  const int wid = blockIdx.x * 4 + wave;
  for (int ch = wid; ch < NPIXP/128; ch += GGRID*4) {
    const int pix0 = ch * 128 + h * 8;
    #pragma unroll
    for (int ks = 0; ks < 8; ++ks) {
      short8 a0 = *(const short8*)(baseA0 + pix0 + ks*16);
      short8 a1 = (short8){0,0,0,0,0,0,0,0};
      if (hi_ok) a1 = *(const short8*)(baseA1 + pix0 + ks*16);
      q00 = __builtin_amdgcn_mfma_f32_32x32x16_bf16(a0, a0, q00, 0, 0, 0);
      q01 = __builtin_amdgcn_mfma_f32_32x32x16_bf16(a0, a1, q01, 0, 0, 0);
      q11 = __builtin_amdgcn_mfma_f32_32x32x16_bf16(a1, a1, q11, 0, 0, 0);
      s0  = __builtin_amdgcn_mfma_f32_32x32x16_bf16(a0, ones, s0, 0, 0, 0);
      s1  = __builtin_amdgcn_mfma_f32_32x32x16_bf16(a1, ones, s1, 0, 0, 0);
    }
  }
  // LDS block-reduce (each (row,col) hit once per wave per quadrant)
  #pragma unroll
  for (int r = 0; r < 16; ++r) {
    int row = (r & 3) + 8*(r >> 2) + 4*h;
    atomicAdd(&gacc[row*64 + cl], q00[r]);
    atomicAdd(&gacc[row*64 + 32 + cl], q01[r]);
    atomicAdd(&gacc[(32 + row)*64 + 32 + cl], q11[r]);
  }
  if (cl == 0) {
    #pragma unroll
    for (int r = 0; r < 16; ++r) {
      int row = (r & 3) + 8*(r >> 2) + 4*h;
      atomicAdd(&sacc[row], s0[r]);
      atomicAdd(&sacc[32 + row], s1[r]);
    }
  }
  __syncthreads();
  for (int i = tid; i < 64*64; i += 256) {
    float v = gacc[i];
    atomicAdd(&G[i], v);
    int r = i >> 6, c2 = i & 63;
    if (r < 32 && c2 >= 32) atomicAdd(&G[c2*64 + r], v);   // mirror lower-left
  }
  if (tid < 64) atomicAdd(&gs[tid], sacc[tid]);
}

// BN1 coefficients from Gram: mean_o = w.m, Var_o = (wGw')/N - mean^2 (b1 cancels)
__global__ __launch_bounds__(256) void bn1_from_gram_kernel(
    const float* __restrict__ G, const float* __restrict__ gs,
    const float* __restrict__ w1,
    const float* __restrict__ g1, const float* __restrict__ be1,
    float* __restrict__ ac) {
  __shared__ float Gl[64*64];
  __shared__ float Wl[C*C];
  __shared__ float Ul[C*C];
  __shared__ float ml[C];
  int tid = threadIdx.x;
  for (int i = tid; i < 64*64; i += 256) Gl[i] = G[i];
  for (int i = tid; i < C*C; i += 256) Wl[i] = w1[i];
  if (tid < C) ml[tid] = gs[tid] * (1.0f/NPIX);
  __syncthreads();
  for (int e = tid; e < C*C; e += 256) {
    int o = e / C, c = e - o*C;
    float s = 0.f;
    for (int c2 = 0; c2 < C; ++c2) s = fmaf(Wl[o*C + c2], Gl[c2*64 + c], s);
    Ul[e] = s;
  }
  __syncthreads();
  if (tid < C) {
    int o = tid;
    float q = 0.f, uw = 0.f;
    for (int c = 0; c < C; ++c) {
      q  = fmaf(Wl[o*C + c], ml[c], q);
      uw = fmaf(Ul[o*C + c], Wl[o*C + c], uw);
    }
    float var = uw * (1.0f/NPIX) - q*q;
    float a = g1[o] * rsqrtf(var + BN_EPS);
    ac[o]     = a;
    ac[C + o] = fmaf(-q, a, be1[o]);
  }
}

// ---------------------------------------------------------------------------
// y2: d2 = w2 . relu(af*(W1 p) + cf) per pixel (MFMA from p_ch); BN2 stats.
// ---------------------------------------------------------------------------
__global__ __launch_bounds__(256) void y2_kernel(
    const unsigned short* __restrict__ p_ch, const float* __restrict__ w1,
    const float* __restrict__ ac, const float* __restrict__ w2,
    float* __restrict__ y2, float* __restrict__ stats2) {
  __shared__ unsigned short Wl[64*64];
  __shared__ float af[64], cf[64], wf[64];
  const int tid = threadIdx.x, wave = tid >> 6, lane = tid & 63;
  for (int idx = tid; idx < 4096; idx += 256) {
    int o = idx >> 6, k = idx & 63;
    float v = (o < C && k < C) ? w1[o*C + k] : 0.f;
    *(unsigned short*)((char*)Wl + (o*128 + ((2*k) ^ ((o & 7) << 4)))) = f2bf(v);
  }
  if (tid < 64) {
    bool ok = tid < C;
    af[tid] = ok ? ac[tid] : 0.f;
    cf[tid] = ok ? ac[C + tid] : 0.f;
    wf[tid] = ok ? w2[tid] : 0.f;
  }
  __syncthreads();
  short8 afr[2][4];
  #pragma unroll
  for (int q = 0; q < 2; ++q)
    #pragma unroll
    for (int ks = 0; ks < 4; ++ks) {
      int row = q*32 + (lane & 31), kb = ks*16 + 8*(lane >> 5);
      afr[q][ks] = *(const short8*)((const char*)Wl + row*128 + ((2*kb) ^ ((row & 7) << 4)));
    }
  const int h = lane >> 5, cl = lane & 31;
  float ss1 = 0.f, ss2 = 0.f;
  const int nchunk = (NPIX + 127)/128;
  for (int ch = blockIdx.x; ch < nchunk; ch += gridDim.x) {
    int col = ch*128 + wave*32 + cl;
    bool cv = col < NPIX;
    int pc = cv ? col : 0;
    short8 bfr[4];
    #pragma unroll
    for (int ks = 0; ks < 4; ++ks) {
      #pragma unroll
      for (int j = 0; j < 8; ++j) {
        int chn = ks*16 + 8*h + j;
        bfr[ks][j] = (chn < C) ? (short)p_ch[(size_t)chn*NPIXP + pc] : (short)0;
      }
    }
    float16 a0 = {}, a1 = {};
    #pragma unroll
    for (int ks = 0; ks < 4; ++ks) {
      a0 = __builtin_amdgcn_mfma_f32_32x32x16_bf16(afr[0][ks], bfr[ks], a0, 0, 0, 0);
      a1 = __builtin_amdgcn_mfma_f32_32x32x16_bf16(afr[1][ks], bfr[ks], a1, 0, 0, 0);
    }
    float ysum = 0.f;
    #pragma unroll
    for (int r = 0; r < 16; ++r) {
      int o0 = (r & 3) + 8*(r >> 2) + 4*h;
      ysum = fmaf(wf[o0], fmaxf(fmaf(af[o0], a0[r], cf[o0]), 0.f), ysum);
      int o1 = o0 + 32;
      ysum = fmaf(wf[o1], fmaxf(fmaf(af[o1], a1[r], cf[o1]), 0.f), ysum);
    }
    ysum += __shfl_xor(ysum, 32);
    bool wr = cv && lane < 32;
    if (wr) {
      y2[col] = ysum;
      ss1 += ysum;
      ss2 = fmaf(ysum, ysum, ss2);
    }
  }
  #pragma unroll
  for (int off = 1; off < 64; off <<= 1) {
    ss1 += __shfl_xor(ss1, off);
    ss2 += __shfl_xor(ss2, off);
  }
  if (lane == 0) {
    atomicAdd(&stats2[(blockIdx.x & 63)*2 + 0], ss1);
    atomicAdd(&stats2[(blockIdx.x & 63)*2 + 1], ss2);
  }
}

__global__ void bn2_final_kernel(const float* __restrict__ stats2,
                                 const float* __restrict__ g2, const float* __restrict__ be2,
                                 float* __restrict__ a2c2) {
  int t = threadIdx.x;   // 64 threads
  float s1 = stats2[t*2], s2 = stats2[t*2 + 1];
  #pragma unroll
  for (int off = 32; off > 0; off >>= 1) {
    s1 += __shfl_down(s1, off);
    s2 += __shfl_down(s2, off);
  }
  if (t == 0) {
    float mean = s1 * (1.f/NPIX);
    float var  = s2 * (1.f/NPIX) - mean*mean;
    float a = g2[0] * rsqrtf(var + BN_EPS);
    a2c2[0] = a;
    a2c2[1] = fmaf(-a, mean, be2[0]);
  }
}

// ---------------------------------------------------------------------------
// r_pool: C_out = relu(a2*y2 + c2) (owner-written), T = C_out/S,
// R = E * fullcorr8x8(T) via separable boxsum of zero-padded T.
// ---------------------------------------------------------------------------
__global__ __launch_bounds__(256) void r_pool_kernel(
    const float* __restrict__ y2, const float* __restrict__ S,
    const float* __restrict__ a2c2, const float* __restrict__ E,
    float* __restrict__ cout, float* __restrict__ R) {
  __shared__ float tin[39][40];
  __shared__ float hs[39][33];
  const int b = blockIdx.z;
  const int i0 = blockIdx.y*32, j0 = blockIdx.x*32;
  const int tid = threadIdx.x;
  const float a2 = a2c2[0], c2 = a2c2[1];
  const float* y2b = y2 + (size_t)b*NSP;
  const float* Sb  = S  + (size_t)b*NSP;
  float* cb = cout + (size_t)b*NSP;
  for (int idx = tid; idx < 39*39; idx += 256) {
    int r = idx / 39, cc = idx - r*39;
    int gi = i0 + r - 7, gj = j0 + cc - 7;
    float t = 0.f;
    if (gi >= 0 && gi < HC && gj >= 0 && gj < WC) {
      float v = fmaxf(fmaf(a2, y2b[gi*WC + gj], c2), 0.f);
      t = v / Sb[gi*WC + gj];
      if (r >= 7 && cc >= 7) cb[gi*WC + gj] = v;
    }
    tin[r][cc] = t;
  }
  __syncthreads();
  for (int idx = tid; idx < 39*32; idx += 256) {
    int r = idx >> 5, j = idx & 31;
    float s = 0.f;
    #pragma unroll
    for (int d = 0; d < 8; ++d) s += tin[r][j + d];
    hs[r][j] = s;
  }
  __syncthreads();
  for (int idx = tid; idx < 32*32; idx += 256) {
    int i = idx >> 5, j = idx & 31;
    size_t gofs = (size_t)b*NIMG + (i0 + i)*W + (j0 + j);
    float s = 0.f;
    #pragma unroll
    for (int d = 0; d < 8; ++d) s += hs[i + d][j];
    R[gofs] = E[gofs] * s;
  }
}

extern "C" void kernel_launch(void* const* d_in, const int* in_sizes, int n_in,
                              void* d_out, int out_size, void* d_ws, size_t ws_size,
                              hipStream_t stream) {
  const float* x   = (const float*)d_in[0];
  const float* w1  = (const float*)d_in[1];
  const float* w2  = (const float*)d_in[3];
  const float* g1  = (const float*)d_in[5];
  const float* be1 = (const float*)d_in[6];
  const float* g2  = (const float*)d_in[7];
  const float* be2 = (const float*)d_in[8];

  float* out_c = (float*)d_out;          // C_out: NPIX floats
  float* out_r = out_c + NPIX;           // R: NM floats

  unsigned short* p_ch = (unsigned short*)d_ws;         // [56][NPIXP] bf16
  float* fbase = (float*)(p_ch + (size_t)C*NPIXP);
  size_t off = 0;
  float* Epart  = fbase + off; off += (size_t)7*NM;
  float* E      = fbase + off; off += NM;
  float* Sarr   = fbase + off; off += NPIX;
  float* y2     = fbase + off; off += NPIX;
  float* G      = fbase + off; off += 64*64;
  float* gs     = fbase + off; off += 64;
  float* stats2 = fbase + off; off += 128;
  float* ac     = fbase + off; off += 112;
  float* a2c2   = fbase + off; off += 2;

  hipMemsetAsync(G, 0, (64*64 + 64 + 128)*sizeof(float), stream);
  padzero_kernel<<<(C*(NPIXP-NPIX) + 255)/256, 256, 0, stream>>>(p_ch);

  pool32_kernel<<<100*B*7, 256, 0, stream>>>(x, Epart, p_ch);

  dim3 sg(10, 10, B);
  se_pool_kernel<<<sg, 256, 0, stream>>>(Epart, E, Sarr);

  gram_kernel<<<GGRID, 256, 0, stream>>>(p_ch, G, gs);
  bn1_from_gram_kernel<<<1, 256, 0, stream>>>(G, gs, w1, g1, be1, ac);
  y2_kernel<<<1536, 256, 0, stream>>>(p_ch, w1, ac, w2, y2, stats2);
  bn2_final_kernel<<<1, 64, 0, stream>>>(stats2, g2, be2, a2c2);

  dim3 rg(10, 10, B);
  r_pool_kernel<<<rg, 256, 0, stream>>>(y2, Sarr, a2c2, E, out_c, out_r);
}